// Round 1
// 629.018 us; speedup vs baseline: 1.2153x; 1.2153x over previous
//
#include <hip/hip_runtime.h>

// MeshAttention gfx950 — round 5: merged-head attention kernel.
// One block per (b, qtile): 512 threads = 8 waves, wave w handles head w.
// dist tile staged ONCE per K-tile (transposed, shared by all heads),
// double-buffered LDS (dist+V), register-prefetched K frags, wave-private pS
// (no barrier between exp and PV), one barrier per K-tile per sweep.
// B=4, H=8, E=1500, D=256, DK=DV=32, P+1=6, mask = dist<=3.

#define E_ 1500
#define D_ 256
#define HH 8
#define BB 4
#define MM (BB * E_)  // 6000
#define KT_ 64
#define NKT_ 24  // 1536 / 64

typedef float f32x4 __attribute__((ext_vector_type(4)));
typedef short short8 __attribute__((ext_vector_type(8)));

static __device__ inline unsigned short f2bf(float f) {
  unsigned u = __float_as_uint(f);
  unsigned r = (u + 0x7fff + ((u >> 16) & 1)) >> 16;
  return (unsigned short)r;
}
static __device__ inline float bf2f(unsigned short u) {
  return __uint_as_float(((unsigned)u) << 16);
}

// ------------------------------------------- transpose: x -> xt f32, xtb bf16
__global__ __launch_bounds__(256) void t0_transpose(const float* __restrict__ x,
                                                    float* __restrict__ xt,
                                                    unsigned short* __restrict__ xtb) {
  __shared__ float tl[32][33];
  const int b = blockIdx.z;
  const int dt = blockIdx.x * 32;
  const int et = blockIdx.y * 32;
  const int tx = threadIdx.x, ty = threadIdx.y;
#pragma unroll
  for (int j = 0; j < 4; j++) {
    int d = dt + ty + j * 8;
    int e = et + tx;
    float v = 0.f;
    if (e < E_) v = x[(size_t)b * D_ * E_ + (size_t)d * E_ + e];
    tl[ty + j * 8][tx] = v;
  }
  __syncthreads();
#pragma unroll
  for (int j = 0; j < 4; j++) {
    int e = et + ty + j * 8;
    int d = dt + tx;
    if (e < E_) {
      float v = tl[tx][ty + j * 8];
      size_t idx = ((size_t)b * E_ + e) * D_ + d;
      xt[idx] = v;
      xtb[idx] = f2bf(v);
    }
  }
}

// ------------------------------------------- weight convert+transpose -> bf16
__global__ __launch_bounds__(256) void t1_wt(const float* __restrict__ Wq,
                                             const float* __restrict__ Wk,
                                             const float* __restrict__ Wv,
                                             const float* __restrict__ Wfc,
                                             unsigned short* __restrict__ WT) {
  __shared__ float tl[32][33];
  const int mat = blockIdx.z;
  const float* W = (mat == 0) ? Wq : (mat == 1) ? Wk : (mat == 2) ? Wv : Wfc;
  const int kt = blockIdx.x * 32, nt = blockIdx.y * 32;
  const int tx = threadIdx.x, ty = threadIdx.y;
#pragma unroll
  for (int j = 0; j < 4; j++)
    tl[ty + j * 8][tx] = W[(size_t)(kt + ty + j * 8) * 256 + nt + tx];
  __syncthreads();
#pragma unroll
  for (int j = 0; j < 4; j++)
    WT[(size_t)mat * 65536 + (size_t)(nt + ty + j * 8) * 256 + kt + tx] =
        f2bf(tl[tx][ty + j * 8]);
}

// ---------------------------------------------------------------- layernorm
__global__ __launch_bounds__(256) void k1_ln(const float* __restrict__ xt,
                                             const float* __restrict__ lnw,
                                             const float* __restrict__ lnb,
                                             unsigned short* __restrict__ qnb) {
  const int m = blockIdx.x;
  const int t = threadIdx.x;
  float v = xt[(size_t)m * D_ + t];
  float s = v, s2 = v * v;
#pragma unroll
  for (int o = 1; o < 64; o <<= 1) {
    s += __shfl_xor(s, o);
    s2 += __shfl_xor(s2, o);
  }
  __shared__ float ps[4], ps2[4], mv[2];
  const int w = t >> 6;
  if ((t & 63) == 0) { ps[w] = s; ps2[w] = s2; }
  __syncthreads();
  if (t == 0) {
    float ts = ps[0] + ps[1] + ps[2] + ps[3];
    float ts2 = ps2[0] + ps2[1] + ps2[2] + ps2[3];
    float mu = ts * (1.f / 256.f);
    float var = ts2 * (1.f / 256.f) - mu * mu;
    mv[0] = mu;
    mv[1] = rsqrtf(var + 1e-6f);
  }
  __syncthreads();
  qnb[(size_t)m * D_ + t] = f2bf((v - mv[0]) * mv[1] * lnw[t] + lnb[t]);
}

// ------------------------------------------------- projections, LDS-free mfma
__global__ __launch_bounds__(256) void kproj(
    const unsigned short* __restrict__ xtb, const unsigned short* __restrict__ qnb,
    const unsigned short* __restrict__ WT, unsigned short* __restrict__ qb,
    unsigned short* __restrict__ kb, unsigned short* __restrict__ vb) {
  const int mat = blockIdx.y >> 2;
  const int n0 = (blockIdx.y & 3) * 64;
  const int m0 = blockIdx.x * 64;
  const int t = threadIdx.x;
  const int w = t >> 6, l = t & 63, quad = l >> 4, l15 = l & 15;
  const unsigned short* A = (mat == 0) ? qnb : xtb;
  const unsigned short* B = WT + (size_t)mat * 65536;
  unsigned short* dst = (mat == 0) ? qb : ((mat == 1) ? kb : vb);
  const float scale = (mat == 0) ? 0.17677669529663687f : 1.0f;

  int mrow = m0 + w * 16 + l15;
  if (mrow > MM - 1) mrow = MM - 1;
  short8 af[8];
#pragma unroll
  for (int kc = 0; kc < 8; kc++)
    af[kc] = *(const short8*)(A + (size_t)mrow * 256 + kc * 32 + quad * 8);

#pragma unroll
  for (int ntile = 0; ntile < 4; ntile++) {
    const int n = n0 + ntile * 16 + l15;
    f32x4 acc = {0.f, 0.f, 0.f, 0.f};
#pragma unroll
    for (int kc = 0; kc < 8; kc++) {
      short8 bf = *(const short8*)(B + (size_t)n * 256 + kc * 32 + quad * 8);
      acc = __builtin_amdgcn_mfma_f32_16x16x32_bf16(af[kc], bf, acc, 0, 0, 0);
    }
#pragma unroll
    for (int r = 0; r < 4; r++) {
      int m = m0 + w * 16 + quad * 4 + r;
      if (m < MM) dst[(size_t)m * 256 + n] = f2bf(acc[r] * scale);
    }
  }
}

// ---------------------------------------------------------------- attention
// grid 188 = b(4) x qtile(47); 512 threads = 8 waves; wave w = head w.
__global__ __launch_bounds__(512, 2) void k2_attn(
    const unsigned short* __restrict__ qb, const unsigned short* __restrict__ kb,
    const unsigned short* __restrict__ vb, const int* __restrict__ dist,
    const float* __restrict__ rpr, float* __restrict__ attn,
    unsigned short* __restrict__ aob, float* __restrict__ asum,
    float* __restrict__ validf) {
  // LDS: 138,624 B total -> 1 block/CU, 8 waves.
  __shared__ unsigned short vT[2][8][2312];  // [buf][head][dv*72 + k], pad: 72=8*9, head stride 2312
  __shared__ unsigned short pS[8][2312];     // wave-private P tile [head][q*72 + k]
  __shared__ int distT[2][2816];             // [buf][k*44 + q]  (transposed dist tile)
  __shared__ float qdrS[8][32][4];           // q . rpr[p], p in 0..3 (only masked p used)
  __shared__ float rinvS[8][32];             // 1/rowsum per (head, q)

  const int blk = blockIdx.x;
  const int b = blk / 47;
  const int qt = blk % 47;
  const int q0 = qt * 32;
  const int t = threadIdx.x;
  const int w = t >> 6, l = t & 63, quad = l >> 4, l15 = l & 15;

  // ---- q_dot_rpr (scaled q, like reference): 1024 entries, 2 per thread
#pragma unroll
  for (int ii = 0; ii < 2; ii++) {
    int id = t + ii * 512;
    int h = id >> 7, rem = id & 127, q = rem >> 2, p = rem & 3;
    int qg = q0 + q;
    float s = 0.f;
    if (qg < E_) {
      const unsigned short* qp = qb + ((size_t)(b * E_ + qg)) * 256 + h * 32;
      for (int d = 0; d < 32; d++) s += bf2f(qp[d]) * rpr[p * 32 + d];
    }
    qdrS[h][q][p] = s;
  }

  // ---- Q fragments (row = q0 + qs*16 + l15, k-chunk = quad*8)
  short8 aq[2];
#pragma unroll
  for (int qs = 0; qs < 2; qs++) {
    int qg = q0 + qs * 16 + l15;
    if (qg > E_ - 1) qg = E_ - 1;
    aq[qs] = *(const short8*)(qb + ((size_t)(b * E_ + qg)) * 256 + w * 32 + quad * 8);
  }

  float rs[2][4] = {{0.f, 0.f, 0.f, 0.f}, {0.f, 0.f, 0.f, 0.f}};
  f32x4 accPV[2][2];
#pragma unroll
  for (int qs = 0; qs < 2; qs++)
#pragma unroll
    for (int dv = 0; dv < 2; dv++) {
      f32x4 z = {0.f, 0.f, 0.f, 0.f};
      accPV[qs][dv] = z;
    }

  short8 kregA[4], kregB[4];

  // ---------------- staging lambdas ----------------
  auto loadD = [&](int kt) -> int4 {
    int qrow = t >> 4, c0 = (t & 15) * 4;
    int qg = q0 + qrow;
    int rq = qg < E_ ? qg : E_ - 1;
    int cb = kt * KT_ + c0;
    int cc2 = cb <= E_ - 4 ? cb : E_ - 4;
    return *(const int4*)(dist + ((size_t)b * E_ + rq) * (size_t)E_ + cc2);
  };
  auto writeD = [&](int kt, int buf, int4 d4) {
    int qrow = t >> 4, c0 = (t & 15) * 4;
    int qg = q0 + qrow;
    int cb = kt * KT_ + c0;
    int da[4] = {d4.x, d4.y, d4.z, d4.w};
#pragma unroll
    for (int j = 0; j < 4; j++) {
      int ok = (qg < E_) & ((cb + j) < E_);
      distT[buf][(c0 + j) * 44 + qrow] = ok ? da[j] : 8;
    }
  };
  auto loadV = [&](int kt, uint4 (&vr)[4]) {
    const int r = t >> 3, hh = t & 7;
    const int kg = kt * KT_ + r;
    const uint4 z = {0u, 0u, 0u, 0u};
    if (kg < E_) {
      const unsigned short* vp = vb + ((size_t)(b * E_ + kg)) * 256 + hh * 32;
      vr[0] = *(const uint4*)(vp);
      vr[1] = *(const uint4*)(vp + 8);
      vr[2] = *(const uint4*)(vp + 16);
      vr[3] = *(const uint4*)(vp + 24);
    } else {
      vr[0] = z; vr[1] = z; vr[2] = z; vr[3] = z;  // avoid NaN*0 in MFMA
    }
  };
  auto writeV = [&](int buf, const uint4 (&vr)[4]) {
    const int r = t >> 3, hh = t & 7;
    union { uint4 u[4]; unsigned short s[32]; } vv;
    vv.u[0] = vr[0]; vv.u[1] = vr[1]; vv.u[2] = vr[2]; vv.u[3] = vr[3];
#pragma unroll
    for (int j = 0; j < 32; j++) vT[buf][hh][j * 72 + r] = vv.s[j];
  };
  auto loadK = [&](int kt, short8 (&kr)[4]) {
#pragma unroll
    for (int ks = 0; ks < 4; ks++) {
      int kg = kt * KT_ + ks * 16 + l15;
      if (kg > E_ - 1) kg = E_ - 1;
      kr[ks] = *(const short8*)(kb + ((size_t)(b * E_ + kg)) * 256 + w * 32 + quad * 8);
    }
  };

  // ---------------- sweep 1 body: QK^T -> exp -> rowsum + PV + validf ----------------
  auto body1 = [&](int kt, short8 (&kcur)[4], short8 (&knxt)[4], int cur) {
    const int k0 = kt * KT_;
    const int nxt = cur ^ 1;
    const bool pf = (kt + 1) < NKT_;
    int4 d4;
    uint4 vr[4];
    if (pf) {
      d4 = loadD(kt + 1);
      loadV(kt + 1, vr);
      loadK(kt + 1, knxt);
    }
    int cc[4] = {0, 0, 0, 0};
#pragma unroll
    for (int qs = 0; qs < 2; qs++) {
#pragma unroll
      for (int ks = 0; ks < 4; ks++) {
        f32x4 z = {0.f, 0.f, 0.f, 0.f};
        f32x4 c = __builtin_amdgcn_mfma_f32_16x16x32_bf16(aq[qs], kcur[ks], z, 0, 0, 0);
        int4 dd4 = *(const int4*)&distT[cur][(ks * 16 + l15) * 44 + qs * 16 + quad * 4];
        int da[4] = {dd4.x, dd4.y, dd4.z, dd4.w};
#pragma unroll
        for (int r = 0; r < 4; r++) {
          int ql = qs * 16 + quad * 4 + r;
          float e = 0.f;
          if (da[r] <= 3) e = __expf(c[r] + qdrS[w][ql][da[r] & 3]);
          rs[qs][r] += e;
          pS[w][ql * 72 + ks * 16 + l15] = f2bf(e);
        }
        if (w == 0)
          cc[ks] += (da[0] <= 3) + (da[1] <= 3) + (da[2] <= 3) + (da[3] <= 3);
      }
    }
    if (w == 0) {
#pragma unroll
      for (int ks = 0; ks < 4; ks++) {
        int v = cc[ks];
        v += __shfl_xor(v, 16);
        v += __shfl_xor(v, 32);
        int kcol = k0 + ks * 16 + l15;
        if (quad == 0 && kcol < E_) atomicAdd(validf + b * E_ + kcol, (float)v);
      }
    }
    // PV: pS is wave-private (written+read by this wave only -> no barrier needed)
#pragma unroll
    for (int kc = 0; kc < 2; kc++) {
      short8 bv0 = *(const short8*)&vT[cur][w][(l15) * 72 + kc * 32 + quad * 8];
      short8 bv1 = *(const short8*)&vT[cur][w][(16 + l15) * 72 + kc * 32 + quad * 8];
#pragma unroll
      for (int qs = 0; qs < 2; qs++) {
        short8 ap = *(const short8*)&pS[w][(qs * 16 + l15) * 72 + kc * 32 + quad * 8];
        accPV[qs][0] = __builtin_amdgcn_mfma_f32_16x16x32_bf16(ap, bv0, accPV[qs][0], 0, 0, 0);
        accPV[qs][1] = __builtin_amdgcn_mfma_f32_16x16x32_bf16(ap, bv1, accPV[qs][1], 0, 0, 0);
      }
    }
    if (pf) {
      writeD(kt + 1, nxt, d4);
      writeV(nxt, vr);
    }
    __syncthreads();
  };

  // ---------------- sweep 2 body: recompute -> normalized attn + colsum ----------------
  auto body2 = [&](int kt, short8 (&kcur)[4], short8 (&knxt)[4], int cur) {
    const int k0 = kt * KT_;
    const int nxt = cur ^ 1;
    const bool pf = (kt + 1) < NKT_;
    int4 d4;
    if (pf) {
      d4 = loadD(kt + 1);
      loadK(kt + 1, knxt);
    }
    float ca[4] = {0.f, 0.f, 0.f, 0.f};
    const size_t abase = ((size_t)(b * HH + w)) * E_;
#pragma unroll
    for (int qs = 0; qs < 2; qs++) {
#pragma unroll
      for (int ks = 0; ks < 4; ks++) {
        f32x4 z = {0.f, 0.f, 0.f, 0.f};
        f32x4 c = __builtin_amdgcn_mfma_f32_16x16x32_bf16(aq[qs], kcur[ks], z, 0, 0, 0);
        int4 dd4 = *(const int4*)&distT[cur][(ks * 16 + l15) * 44 + qs * 16 + quad * 4];
        int da[4] = {dd4.x, dd4.y, dd4.z, dd4.w};
        int kcol = k0 + ks * 16 + l15;
#pragma unroll
        for (int r = 0; r < 4; r++) {
          int ql = qs * 16 + quad * 4 + r;
          float p = 0.f;
          if (da[r] <= 3)
            p = __expf(c[r] + qdrS[w][ql][da[r] & 3]) * rinvS[w][ql];
          ca[ks] += p;
          int qg = q0 + ql;
          if (qg < E_ && kcol < E_) attn[(abase + qg) * E_ + kcol] = p;
        }
      }
    }
#pragma unroll
    for (int ks = 0; ks < 4; ks++) {
      float v = ca[ks];
      v += __shfl_xor(v, 16);
      v += __shfl_xor(v, 32);
      int kcol = k0 + ks * 16 + l15;
      if (quad == 0 && kcol < E_) atomicAdd(asum + b * E_ + kcol, v);
    }
    if (pf) writeD(kt + 1, nxt, d4);
    __syncthreads();
  };

  // ================= sweep 1 =================
  {
    int4 d4 = loadD(0);
    uint4 vr[4];
    loadV(0, vr);
    loadK(0, kregA);
    writeD(0, 0, d4);
    writeV(0, vr);
  }
  __syncthreads();
  for (int kt = 0; kt < NKT_; kt += 2) {
    body1(kt, kregA, kregB, 0);
    body1(kt + 1, kregB, kregA, 1);
  }

  // ---- row sums -> rinv
#pragma unroll
  for (int qs = 0; qs < 2; qs++)
#pragma unroll
    for (int r = 0; r < 4; r++) {
      float v = rs[qs][r];
      v += __shfl_xor(v, 1);
      v += __shfl_xor(v, 2);
      v += __shfl_xor(v, 4);
      v += __shfl_xor(v, 8);
      if (l15 == 0) rinvS[w][qs * 16 + quad * 4 + r] = v;
    }
  __syncthreads();
  if (t < 256) {
    int h = t >> 5, q = t & 31;
    float s = rinvS[h][q];
    rinvS[h][q] = (s > 0.f) ? 1.f / s : 0.f;
  }
  __syncthreads();

  // ---- ao = PV * rinv (bf16)
#pragma unroll
  for (int qs = 0; qs < 2; qs++)
#pragma unroll
    for (int dv = 0; dv < 2; dv++) {
      f32x4 a = accPV[qs][dv];
#pragma unroll
      for (int r = 0; r < 4; r++) {
        int ql = qs * 16 + quad * 4 + r;
        int qg = q0 + ql;
        if (qg < E_)
          aob[((size_t)(b * E_ + qg)) * 256 + w * 32 + dv * 16 + l15] =
              f2bf(a[r] * rinvS[w][ql]);
      }
    }

  // ================= sweep 2 =================
  {
    int4 d4 = loadD(0);
    loadK(0, kregA);
    writeD(0, 0, d4);
  }
  __syncthreads();
  for (int kt = 0; kt < NKT_; kt += 2) {
    body2(kt, kregA, kregB, 0);
    body2(kt + 1, kregB, kregA, 1);
  }
}

// ------------------------------------------- FC + residual, LDS-free mfma
__global__ __launch_bounds__(256) void k_fc(const unsigned short* __restrict__ aob,
                                            const unsigned short* __restrict__ WT,
                                            const float* __restrict__ x,
                                            float* __restrict__ xout) {
  const int n0 = blockIdx.y * 64;
  const int m0 = blockIdx.x * 64;
  const int t = threadIdx.x;
  const int w = t >> 6, l = t & 63, quad = l >> 4, l15 = l & 15;
  const unsigned short* B = WT + (size_t)3 * 65536;

  int mrow = m0 + w * 16 + l15;
  if (mrow > MM - 1) mrow = MM - 1;
  short8 af[8];
#pragma unroll
  for (int kc = 0; kc < 8; kc++)
    af[kc] = *(const short8*)(aob + (size_t)mrow * 256 + kc * 32 + quad * 8);

#pragma unroll
  for (int ntile = 0; ntile < 4; ntile++) {
    const int nc = n0 + ntile * 16 + l15;
    f32x4 acc = {0.f, 0.f, 0.f, 0.f};
#pragma unroll
    for (int kc = 0; kc < 8; kc++) {
      short8 bf = *(const short8*)(B + (size_t)nc * 256 + kc * 32 + quad * 8);
      acc = __builtin_amdgcn_mfma_f32_16x16x32_bf16(af[kc], bf, acc, 0, 0, 0);
    }
    int m = m0 + w * 16 + quad * 4;
    if (m < MM) {
      int bb = m / E_, e = m - bb * E_;
      size_t idx = ((size_t)bb * 256 + nc) * E_ + e;
      float4 rx = *(const float4*)(x + idx);
      *(float4*)(xout + idx) = make_float4(acc[0] + rx.x, acc[1] + rx.y,
                                           acc[2] + rx.z, acc[3] + rx.w);
    }
  }
}

__global__ __launch_bounds__(256) void k5_div(const float* __restrict__ asum,
                                              const float* __restrict__ validf,
                                              float* __restrict__ ape) {
  int i = blockIdx.x * 256 + threadIdx.x;
  if (i < BB * E_) ape[i] = asum[i] / validf[i];
}

// ---------------------------------------------------------------- launcher
extern "C" void kernel_launch(void* const* d_in, const int* in_sizes, int n_in,
                              void* d_out, int out_size, void* d_ws,
                              size_t ws_size, hipStream_t stream) {
  const float* x = (const float*)d_in[0];
  const int* dist = (const int*)d_in[1];
  const float* Wq = (const float*)d_in[2];
  const float* Wk = (const float*)d_in[3];
  const float* Wv = (const float*)d_in[4];
  const float* Wfc = (const float*)d_in[5];
  const float* lnw = (const float*)d_in[6];
  const float* lnb = (const float*)d_in[7];
  const float* rpr = (const float*)d_in[8];

  float* out0 = (float*)d_out;
  float* attn = out0 + 1536000;
  float* ape = out0 + 73536000;

  float* ws = (float*)d_ws;
  float* xt = ws;                                            // [6000,256] f32
  unsigned short* xtb = (unsigned short*)(ws + 1536000);     // bf16
  unsigned short* qnb = (unsigned short*)(ws + 2304000);     // bf16
  unsigned short* qb = (unsigned short*)(ws + 3072000);      // bf16
  unsigned short* kb = (unsigned short*)(ws + 3840000);      // bf16
  unsigned short* vb = (unsigned short*)(ws + 4608000);      // bf16
  unsigned short* aob = (unsigned short*)(ws + 5376000);     // bf16
  unsigned short* WT = (unsigned short*)(ws + 6144000);      // [4,256,256] bf16
  float* asum = ws + 6275072;                                // [6000]
  float* validf = ws + 6281072;                              // [6000]

  hipMemsetAsync(asum, 0, 12000 * sizeof(float), stream);

  t0_transpose<<<dim3(8, 47, 4), dim3(32, 8), 0, stream>>>(x, xt, xtb);
  t1_wt<<<dim3(8, 8, 4), dim3(32, 8), 0, stream>>>(Wq, Wk, Wv, Wfc, WT);
  k1_ln<<<MM, 256, 0, stream>>>(xt, lnw, lnb, qnb);
  kproj<<<dim3(94, 12), 256, 0, stream>>>(xtb, qnb, WT, qb, kb, vb);
  k2_attn<<<188, 512, 0, stream>>>(qb, kb, vb, dist, rpr, attn, aob, asum,
                                   validf);
  k_fc<<<dim3(94, 4), 256, 0, stream>>>(aob, WT, x, out0);
  k5_div<<<24, 256, 0, stream>>>(asum, validf, ape);
}